// Round 8
// baseline (451.997 us; speedup 1.0000x reference)
//
#include <hip/hip_runtime.h>
#include <stdint.h>
#include <math.h>

#define T_SEQ 2048
#define NHEAD 16
#define HD 64
#define DMODEL 1024
#define CDIM 1088
#define MROWS 4096

typedef uint16_t u16;
typedef __bf16 b8v __attribute__((ext_vector_type(8)));
typedef float f4v __attribute__((ext_vector_type(4)));

typedef __attribute__((address_space(3))) void lds_void;
typedef const __attribute__((address_space(1))) void glb_void;

__device__ __forceinline__ float b2f(u16 u) {
  union { uint32_t i; float f; } c; c.i = ((uint32_t)u) << 16; return c.f;
}
__device__ __forceinline__ u16 f2b(float f) {
  union { float f; uint32_t i; } c; c.f = f;
  uint32_t x = c.i;
  return (u16)((x + 0x7fffu + ((x >> 16) & 1u)) >> 16);
}
__device__ __forceinline__ float gelu_f(float x) {
  return 0.5f * x * (1.0f + erff(x * 0.70710678118654752f));
}

// ---------------- time MLP (f32 in, f32 out) ---------------------------------
__global__ void time_mlp_kernel(const float* __restrict__ t, const float* __restrict__ w1,
                                const float* __restrict__ b1, const float* __restrict__ w2,
                                const float* __restrict__ b2, float* __restrict__ temb) {
  __shared__ float h1[2][64];
  int tid = threadIdx.x;            // 128 threads
  int b = tid >> 6, i = tid & 63;
  float tv = t[b];
  h1[b][i] = gelu_f(tv * w1[i] + b1[i]);
  __syncthreads();
  float acc = b2[i];
  for (int k = 0; k < 64; ++k) acc += h1[b][k] * w2[k * 64 + i];
  temb[b * 64 + i] = acc;
}

// ---------------- transpose + cast: src f32[R][C] -> dst bf16[C][R] ----------
__global__ __launch_bounds__(256) void transpose_kernel(const float* __restrict__ src,
                                                        u16* __restrict__ dst,
                                                        int R, int C) {
  __shared__ u16 tile[32][33];
  int tx = threadIdx.x & 31, ty = threadIdx.x >> 5;   // ty 0..7
  int c0 = blockIdx.x * 32, r0 = blockIdx.y * 32;
#pragma unroll
  for (int i = 0; i < 4; ++i) {
    int r = ty + i * 8;
    tile[r][tx] = f2b(src[(size_t)(r0 + r) * C + c0 + tx]);
  }
  __syncthreads();
#pragma unroll
  for (int i = 0; i < 4; ++i) {
    int c = ty + i * 8;
    dst[(size_t)(c0 + c) * R + r0 + tx] = tile[tx][c];
  }
}

// ---------------- fused concat(zin, t_emb) + LayerNorm -> bf16 ---------------
__global__ __launch_bounds__(256) void ln_concat_kernel(const float* __restrict__ zf,
                                                        const u16* __restrict__ zb,
                                                        const float* __restrict__ temb,
                                                        const float* __restrict__ w,
                                                        const float* __restrict__ bvec,
                                                        u16* __restrict__ xout,
                                                        int in_f32) {
  __shared__ float red[4];
  int row = blockIdx.x;
  int b = row / T_SEQ;
  int tid = threadIdx.x;
  float v[5];
  float sum = 0.f;
#pragma unroll
  for (int i = 0; i < 5; ++i) {
    int c = tid + i * 256;
    float val = 0.f;
    if (c < CDIM) {
      if (c < DMODEL)
        val = in_f32 ? zf[(size_t)row * DMODEL + c] : b2f(zb[(size_t)row * DMODEL + c]);
      else
        val = temb[b * 64 + (c - DMODEL)];
    }
    v[i] = val;
    sum += val;
  }
#pragma unroll
  for (int off = 32; off; off >>= 1) sum += __shfl_xor(sum, off, 64);
  int wv = tid >> 6, ln = tid & 63;
  if (ln == 0) red[wv] = sum;
  __syncthreads();
  float mean = (red[0] + red[1] + red[2] + red[3]) * (1.0f / CDIM);
  __syncthreads();
  float sq = 0.f;
#pragma unroll
  for (int i = 0; i < 5; ++i) {
    int c = tid + i * 256;
    if (c < CDIM) { float d = v[i] - mean; sq += d * d; }
  }
#pragma unroll
  for (int off = 32; off; off >>= 1) sq += __shfl_xor(sq, off, 64);
  if (ln == 0) red[wv] = sq;
  __syncthreads();
  float inv = rsqrtf((red[0] + red[1] + red[2] + red[3]) * (1.0f / CDIM) + 1e-5f);
#pragma unroll
  for (int i = 0; i < 5; ++i) {
    int c = tid + i * 256;
    if (c < CDIM)
      xout[(size_t)row * CDIM + c] = f2b((v[i] - mean) * inv * w[c] + bvec[c]);
  }
}

// ---------------- GEMM: C[M][N] = act(A[M][K] @ Bt[N][K]^T + bias) -----------
// BK=64 double-buffered single-barrier K-loop, global_load_lds width=16.
// Compute phase (~32 MFMA + 16 ds_read_b128) >= load latency -> prefetch covered.
__global__ __launch_bounds__(256) void gemm_bt_kernel(const u16* __restrict__ A,
                                                      const u16* __restrict__ Bt,
                                                      const float* __restrict__ bias,
                                                      void* __restrict__ Cout,
                                                      int M, int N, int K,
                                                      int do_gelu, int out_f32) {
  __shared__ u16 As[2][128 * 64];
  __shared__ u16 Bs[2][128 * 64];
  const int tid = threadIdx.x;
  const int wave = tid >> 6, lane = tid & 63;
  const int wr = wave >> 1, wc = wave & 1;
  const int m0 = blockIdx.x * 128;
  const int n0 = blockIdx.y * 128;
  const int lrow = lane & 15, quad = lane >> 4;
  const int srow = lane >> 3, sseg = lane & 7;   // 8 rows x 8 segs of 8 elems

  // wave stages rows [wave*32, wave*32+32): 4 instrs A + 4 instrs B per tile
  const u16* gA = A  + (size_t)(m0 + wave * 32 + srow) * K + sseg * 8;
  const u16* gB = Bt + (size_t)(n0 + wave * 32 + srow) * K + sseg * 8;

  f4v acc[4][4] = {};

  // prologue: stage tile 0 into buf 0
#pragma unroll
  for (int i = 0; i < 4; ++i) {
    __builtin_amdgcn_global_load_lds((glb_void*)(gA + (size_t)(i * 8) * K),
                                     (lds_void*)&As[0][(wave * 32 + i * 8) * 64], 16, 0, 0);
    __builtin_amdgcn_global_load_lds((glb_void*)(gB + (size_t)(i * 8) * K),
                                     (lds_void*)&Bs[0][(wave * 32 + i * 8) * 64], 16, 0, 0);
  }

  int cur = 0;
  for (int k0 = 0; k0 < K; k0 += 64) {
    __syncthreads();   // buf[cur] ready; buf[cur^1] reads from last iter done
    if (k0 + 64 < K) {
      int nxt = cur ^ 1;
#pragma unroll
      for (int i = 0; i < 4; ++i) {
        __builtin_amdgcn_global_load_lds((glb_void*)(gA + (size_t)(i * 8) * K + k0 + 64),
                                         (lds_void*)&As[nxt][(wave * 32 + i * 8) * 64], 16, 0, 0);
        __builtin_amdgcn_global_load_lds((glb_void*)(gB + (size_t)(i * 8) * K + k0 + 64),
                                         (lds_void*)&Bs[nxt][(wave * 32 + i * 8) * 64], 16, 0, 0);
      }
    }
#pragma unroll
    for (int kk = 0; kk < 2; ++kk) {
      b8v af[4], bfr[4];
#pragma unroll
      for (int mi = 0; mi < 4; ++mi)
        af[mi] = *(const b8v*)(&As[cur][(wr * 64 + mi * 16 + lrow) * 64 + kk * 32 + quad * 8]);
#pragma unroll
      for (int ni = 0; ni < 4; ++ni)
        bfr[ni] = *(const b8v*)(&Bs[cur][(wc * 64 + ni * 16 + lrow) * 64 + kk * 32 + quad * 8]);
#pragma unroll
      for (int mi = 0; mi < 4; ++mi)
#pragma unroll
        for (int ni = 0; ni < 4; ++ni)
          acc[mi][ni] = __builtin_amdgcn_mfma_f32_16x16x32_bf16(af[mi], bfr[ni], acc[mi][ni], 0, 0, 0);
    }
    cur ^= 1;
  }

#pragma unroll
  for (int mi = 0; mi < 4; ++mi) {
#pragma unroll
    for (int ni = 0; ni < 4; ++ni) {
      int gcol = n0 + wc * 64 + ni * 16 + lrow;
      float bv = bias[gcol];
#pragma unroll
      for (int r = 0; r < 4; ++r) {
        int grow = m0 + wr * 64 + mi * 16 + quad * 4 + r;
        float v = acc[mi][ni][r] + bv;
        if (do_gelu) v = gelu_f(v);
        if (out_f32)
          ((float*)Cout)[(size_t)grow * N + gcol] = v;
        else
          ((u16*)Cout)[(size_t)grow * N + gcol] = f2b(v);
      }
    }
  }
}

// ---------------- MFMA flash attention (S^T / O^T formulation) ---------------
__global__ __launch_bounds__(256) void attn_mfma_kernel(const u16* __restrict__ qkv,
                                                        u16* __restrict__ y) {
  __shared__ u16 Ks[64 * 72];           // K row-major  [key][d]
  __shared__ u16 Vts[64 * 72];          // V transposed [d][key^swz]
  __shared__ u16 Ps[64 * 72];           // P row-major  [q_local][key]
  const int bh = blockIdx.x;
  const int b = bh >> 4, h = bh & 15;
  const int qt = 31 - blockIdx.y;       // heavy tiles first (LPT)
  const int tid = threadIdx.x, w = tid >> 6, lane = tid & 63;
  const int lrow = lane & 15, quad = lane >> 4;
  const int q0 = qt * 64;
  const int qg = q0 + w * 16 + lrow;

  b8v qf[2];
#pragma unroll
  for (int dc = 0; dc < 2; ++dc)
    qf[dc] = *(const b8v*)(qkv + (size_t)(b * T_SEQ + qg) * 3072 + h * 64 + dc * 32 + quad * 8);

  f4v oacc[4] = {};
  float mrun = -__builtin_inff(), lrun = 0.f;

  const int nch = qt + 1;
  for (int ct = 0; ct < nch; ++ct) {
    __syncthreads();
    {
      int r = tid >> 2, sg = tid & 3;
      const u16* src = qkv + (size_t)(b * T_SEQ + ct * 64 + r) * 3072 + h * 64 + 1024 + sg * 16;
      *(uint4*)(&Ks[r * 72 + sg * 16]) = *(const uint4*)(src);
      *(uint4*)(&Ks[r * 72 + sg * 16 + 8]) = *(const uint4*)(src + 8);
    }
    {
      int pr = tid >> 3, dsg = tid & 7;
      const u16* v0 = qkv + (size_t)(b * T_SEQ + ct * 64 + 2 * pr) * 3072 + h * 64 + 2048 + dsg * 8;
      uint4 a = *(const uint4*)(v0);
      uint4 bb = *(const uint4*)(v0 + 3072);
      uint32_t aw[4] = {a.x, a.y, a.z, a.w};
      uint32_t bw[4] = {bb.x, bb.y, bb.z, bb.w};
#pragma unroll
      for (int j = 0; j < 8; ++j) {
        int d = dsg * 8 + j;
        u16 ae = (u16)(aw[j >> 1] >> ((j & 1) * 16));
        u16 be = (u16)(bw[j >> 1] >> ((j & 1) * 16));
        int keyp = (2 * pr) ^ (((d >> 3) & 7) * 8);
        *(uint32_t*)(&Vts[d * 72 + keyp]) = (uint32_t)ae | ((uint32_t)be << 16);
      }
    }
    __syncthreads();

    f4v sacc[4] = {};
#pragma unroll
    for (int ks = 0; ks < 4; ++ks)
#pragma unroll
      for (int dc = 0; dc < 2; ++dc) {
        b8v kf = *(const b8v*)(&Ks[(ks * 16 + lrow) * 72 + dc * 32 + quad * 8]);
        sacc[ks] = __builtin_amdgcn_mfma_f32_16x16x32_bf16(kf, qf[dc], sacc[ks], 0, 0, 0);
      }

    bool diag = (ct == qt);
#pragma unroll
    for (int ks = 0; ks < 4; ++ks)
#pragma unroll
      for (int r = 0; r < 4; ++r) {
        float v = sacc[ks][r] * 0.125f;
        int key = ct * 64 + ks * 16 + quad * 4 + r;
        if (diag && key > qg) v = -__builtin_inff();
        sacc[ks][r] = v;
      }

    float rmax = sacc[0][0];
#pragma unroll
    for (int ks = 0; ks < 4; ++ks)
#pragma unroll
      for (int r = 0; r < 4; ++r) rmax = fmaxf(rmax, sacc[ks][r]);
    rmax = fmaxf(rmax, __shfl_xor(rmax, 16, 64));
    rmax = fmaxf(rmax, __shfl_xor(rmax, 32, 64));
    float mn = fmaxf(mrun, rmax);
    float al = __expf(mrun - mn);
    mrun = mn;
    float psum = 0.f;
#pragma unroll
    for (int ks = 0; ks < 4; ++ks)
#pragma unroll
      for (int r = 0; r < 4; ++r) {
        float p = __expf(sacc[ks][r] - mn);
        sacc[ks][r] = p;
        psum += p;
      }
    psum += __shfl_xor(psum, 16, 64);
    psum += __shfl_xor(psum, 32, 64);
    lrun = lrun * al + psum;
#pragma unroll
    for (int ds = 0; ds < 4; ++ds) oacc[ds] *= al;

#pragma unroll
    for (int ks = 0; ks < 4; ++ks) {
      ushort4 pw;
      pw.x = f2b(sacc[ks][0]); pw.y = f2b(sacc[ks][1]);
      pw.z = f2b(sacc[ks][2]); pw.w = f2b(sacc[ks][3]);
      *(ushort4*)(&Ps[(w * 16 + lrow) * 72 + ks * 16 + quad * 4]) = pw;
    }

    b8v pf[2];
#pragma unroll
    for (int kc = 0; kc < 2; ++kc)
      pf[kc] = *(const b8v*)(&Ps[(w * 16 + lrow) * 72 + kc * 32 + quad * 8]);
#pragma unroll
    for (int ds = 0; ds < 4; ++ds)
#pragma unroll
      for (int kc = 0; kc < 2; ++kc) {
        int d = ds * 16 + lrow;
        int off = (kc * 32 + quad * 8) ^ (((d >> 3) & 7) * 8);
        b8v vfv = *(const b8v*)(&Vts[d * 72 + off]);
        oacc[ds] = __builtin_amdgcn_mfma_f32_16x16x32_bf16(vfv, pf[kc], oacc[ds], 0, 0, 0);
      }
  }

  float rinv = 1.0f / lrun;
  u16* yrow = y + (size_t)(b * T_SEQ + qg) * DMODEL + h * 64;
#pragma unroll
  for (int ds = 0; ds < 4; ++ds) {
    ushort4 ov;
    ov.x = f2b(oacc[ds][0] * rinv);
    ov.y = f2b(oacc[ds][1] * rinv);
    ov.z = f2b(oacc[ds][2] * rinv);
    ov.w = f2b(oacc[ds][3] * rinv);
    *(ushort4*)(yrow + ds * 16 + quad * 4) = ov;
  }
}

// ----------------------------------------------------------------------------
extern "C" void kernel_launch(void* const* d_in, const int* in_sizes, int n_in,
                              void* d_out, int out_size, void* d_ws, size_t ws_size,
                              hipStream_t stream) {
  const float* z      = (const float*)d_in[0];
  const float* t      = (const float*)d_in[1];
  const float* w_t1   = (const float*)d_in[2];
  const float* b_t1   = (const float*)d_in[3];
  const float* w_t2   = (const float*)d_in[4];
  const float* b_t2   = (const float*)d_in[5];
  const float* ln_a_w = (const float*)d_in[6];
  const float* ln_a_b = (const float*)d_in[7];
  const float* w_attn = (const float*)d_in[8];
  const float* b_attn = (const float*)d_in[9];
  const float* w_proj = (const float*)d_in[10];
  const float* b_proj = (const float*)d_in[11];
  const float* ln_m_w = (const float*)d_in[12];
  const float* ln_m_b = (const float*)d_in[13];
  const float* w_fc   = (const float*)d_in[14];
  const float* b_fc   = (const float*)d_in[15];
  const float* w_fc2  = (const float*)d_in[16];
  const float* b_fc2  = (const float*)d_in[17];

  char* ws = (char*)d_ws;
  float* temb  = (float*)ws;
  u16* wT_attn = (u16*)(ws + 1024);
  u16* wT_proj = wT_attn + (size_t)3072 * 1088;
  u16* wT_fc   = wT_proj + (size_t)1024 * 1024;
  u16* wT_fc2  = wT_fc   + (size_t)4096 * 1088;
  u16* xbuf    = wT_fc2  + (size_t)1024 * 4096;
  u16* big     = xbuf    + (size_t)4096 * 1088;
  u16* ybuf    = big     + (size_t)4096 * 4096;
  u16* hbuf    = ybuf    + (size_t)4096 * 1024;

  time_mlp_kernel<<<dim3(1), dim3(128), 0, stream>>>(t, w_t1, b_t1, w_t2, b_t2, temb);

  transpose_kernel<<<dim3(3072 / 32, 1088 / 32), dim3(256), 0, stream>>>(w_attn, wT_attn, 1088, 3072);
  transpose_kernel<<<dim3(1024 / 32, 1024 / 32), dim3(256), 0, stream>>>(w_proj, wT_proj, 1024, 1024);
  transpose_kernel<<<dim3(4096 / 32, 1088 / 32), dim3(256), 0, stream>>>(w_fc, wT_fc, 1088, 4096);
  transpose_kernel<<<dim3(1024 / 32, 4096 / 32), dim3(256), 0, stream>>>(w_fc2, wT_fc2, 4096, 1024);

  ln_concat_kernel<<<dim3(MROWS), dim3(256), 0, stream>>>(z, (const u16*)nullptr, temb,
                                                          ln_a_w, ln_a_b, xbuf, 1);

  gemm_bt_kernel<<<dim3(MROWS / 128, 3072 / 128), dim3(256), 0, stream>>>(
      xbuf, wT_attn, b_attn, big, MROWS, 3072, 1088, 0, 0);

  attn_mfma_kernel<<<dim3(32, 32), dim3(256), 0, stream>>>(big, ybuf);

  gemm_bt_kernel<<<dim3(MROWS / 128, 1024 / 128), dim3(256), 0, stream>>>(
      ybuf, wT_proj, b_proj, hbuf, MROWS, 1024, 1024, 0, 0);

  ln_concat_kernel<<<dim3(MROWS), dim3(256), 0, stream>>>((const float*)nullptr, hbuf, temb,
                                                          ln_m_w, ln_m_b, xbuf, 0);

  gemm_bt_kernel<<<dim3(MROWS / 128, 4096 / 128), dim3(256), 0, stream>>>(
      xbuf, wT_fc, b_fc, big, MROWS, 4096, 1088, 1, 0);

  gemm_bt_kernel<<<dim3(MROWS / 128, 1024 / 128), dim3(256), 0, stream>>>(
      big, wT_fc2, b_fc2, d_out, MROWS, 1024, 4096, 0, 1);
}

// Round 9
// 406.970 us; speedup vs baseline: 1.1106x; 1.1106x over previous
//
#include <hip/hip_runtime.h>
#include <stdint.h>
#include <math.h>

#define T_SEQ 2048
#define NHEAD 16
#define HD 64
#define DMODEL 1024
#define CDIM 1088
#define MROWS 4096

typedef uint16_t u16;
typedef __bf16 b8v __attribute__((ext_vector_type(8)));
typedef float f4v __attribute__((ext_vector_type(4)));

typedef __attribute__((address_space(3))) void lds_void;
typedef const __attribute__((address_space(1))) void glb_void;

__device__ __forceinline__ float b2f(u16 u) {
  union { uint32_t i; float f; } c; c.i = ((uint32_t)u) << 16; return c.f;
}
__device__ __forceinline__ u16 f2b(float f) {
  union { float f; uint32_t i; } c; c.f = f;
  uint32_t x = c.i;
  return (u16)((x + 0x7fffu + ((x >> 16) & 1u)) >> 16);
}
__device__ __forceinline__ float gelu_f(float x) {
  return 0.5f * x * (1.0f + erff(x * 0.70710678118654752f));
}

// ---------------- time MLP (f32 in, f32 out) ---------------------------------
__global__ void time_mlp_kernel(const float* __restrict__ t, const float* __restrict__ w1,
                                const float* __restrict__ b1, const float* __restrict__ w2,
                                const float* __restrict__ b2, float* __restrict__ temb) {
  __shared__ float h1[2][64];
  int tid = threadIdx.x;            // 128 threads
  int b = tid >> 6, i = tid & 63;
  float tv = t[b];
  h1[b][i] = gelu_f(tv * w1[i] + b1[i]);
  __syncthreads();
  float acc = b2[i];
  for (int k = 0; k < 64; ++k) acc += h1[b][k] * w2[k * 64 + i];
  temb[b * 64 + i] = acc;
}

// ---------------- transpose + cast: src f32[R][C] -> dst bf16[C][R] ----------
__global__ __launch_bounds__(256) void transpose_kernel(const float* __restrict__ src,
                                                        u16* __restrict__ dst,
                                                        int R, int C) {
  __shared__ u16 tile[32][33];
  int tx = threadIdx.x & 31, ty = threadIdx.x >> 5;   // ty 0..7
  int c0 = blockIdx.x * 32, r0 = blockIdx.y * 32;
#pragma unroll
  for (int i = 0; i < 4; ++i) {
    int r = ty + i * 8;
    tile[r][tx] = f2b(src[(size_t)(r0 + r) * C + c0 + tx]);
  }
  __syncthreads();
#pragma unroll
  for (int i = 0; i < 4; ++i) {
    int c = ty + i * 8;
    dst[(size_t)(c0 + c) * R + r0 + tx] = tile[tx][c];
  }
}

// ---------------- add two f32 buffers -> f32 out -----------------------------
__global__ __launch_bounds__(256) void add2_kernel(const float4* __restrict__ a,
                                                   const float4* __restrict__ b,
                                                   float4* __restrict__ o, int n4) {
  int i = blockIdx.x * 256 + threadIdx.x;
  if (i < n4) {
    float4 x = a[i], y = b[i];
    o[i] = float4{x.x + y.x, x.y + y.y, x.z + y.z, x.w + y.w};
  }
}

// ---------------- fused concat + LayerNorm -> bf16 ---------------------------
// mode 0: z from zb (bf16); mode 1: z from zf (f32); mode 2: z = zf + zf2 (f32)
__global__ __launch_bounds__(256) void ln_concat_kernel(const float* __restrict__ zf,
                                                        const float* __restrict__ zf2,
                                                        const u16* __restrict__ zb,
                                                        const float* __restrict__ temb,
                                                        const float* __restrict__ w,
                                                        const float* __restrict__ bvec,
                                                        u16* __restrict__ xout,
                                                        int mode) {
  __shared__ float red[4];
  int row = blockIdx.x;
  int b = row / T_SEQ;
  int tid = threadIdx.x;
  float v[5];
  float sum = 0.f;
#pragma unroll
  for (int i = 0; i < 5; ++i) {
    int c = tid + i * 256;
    float val = 0.f;
    if (c < CDIM) {
      if (c < DMODEL) {
        size_t idx = (size_t)row * DMODEL + c;
        if (mode == 0) val = b2f(zb[idx]);
        else if (mode == 1) val = zf[idx];
        else val = zf[idx] + zf2[idx];
      } else {
        val = temb[b * 64 + (c - DMODEL)];
      }
    }
    v[i] = val;
    sum += val;
  }
#pragma unroll
  for (int off = 32; off; off >>= 1) sum += __shfl_xor(sum, off, 64);
  int wv = tid >> 6, ln = tid & 63;
  if (ln == 0) red[wv] = sum;
  __syncthreads();
  float mean = (red[0] + red[1] + red[2] + red[3]) * (1.0f / CDIM);
  __syncthreads();
  float sq = 0.f;
#pragma unroll
  for (int i = 0; i < 5; ++i) {
    int c = tid + i * 256;
    if (c < CDIM) { float d = v[i] - mean; sq += d * d; }
  }
#pragma unroll
  for (int off = 32; off; off >>= 1) sq += __shfl_xor(sq, off, 64);
  if (ln == 0) red[wv] = sq;
  __syncthreads();
  float inv = rsqrtf((red[0] + red[1] + red[2] + red[3]) * (1.0f / CDIM) + 1e-5f);
#pragma unroll
  for (int i = 0; i < 5; ++i) {
    int c = tid + i * 256;
    if (c < CDIM)
      xout[(size_t)row * CDIM + c] = f2b((v[i] - mean) * inv * w[c] + bvec[c]);
  }
}

// ---------------- GEMM: C[M][N] = act(A[M][K] @ Bt[N][K]^T + bias) -----------
// BK=32 double-buffered single-barrier K-loop, global_load_lds width=16.
__global__ __launch_bounds__(256) void gemm_bt_kernel(const u16* __restrict__ A,
                                                      const u16* __restrict__ Bt,
                                                      const float* __restrict__ bias,
                                                      void* __restrict__ Cout,
                                                      int M, int N, int K,
                                                      int do_gelu, int out_f32) {
  __shared__ u16 As[2][128 * 32];
  __shared__ u16 Bs[2][128 * 32];
  const int tid = threadIdx.x;
  const int wave = tid >> 6, lane = tid & 63;
  const int wr = wave >> 1, wc = wave & 1;
  const int m0 = blockIdx.x * 128;
  const int n0 = blockIdx.y * 128;
  const int lrow = lane & 15, quad = lane >> 4;
  const int srow = lane >> 2, sseg = lane & 3;

  const u16* gA0 = A  + (size_t)(m0 + wave * 32 + srow) * K + sseg * 8;
  const u16* gA1 = gA0 + (size_t)16 * K;
  const u16* gB0 = Bt + (size_t)(n0 + wave * 32 + srow) * K + sseg * 8;
  const u16* gB1 = gB0 + (size_t)16 * K;
  const int la0 = (wave * 32) * 32, la1 = (wave * 32 + 16) * 32;

  f4v acc[4][4] = {};

  __builtin_amdgcn_global_load_lds((glb_void*)gA0, (lds_void*)&As[0][la0], 16, 0, 0);
  __builtin_amdgcn_global_load_lds((glb_void*)gA1, (lds_void*)&As[0][la1], 16, 0, 0);
  __builtin_amdgcn_global_load_lds((glb_void*)gB0, (lds_void*)&Bs[0][la0], 16, 0, 0);
  __builtin_amdgcn_global_load_lds((glb_void*)gB1, (lds_void*)&Bs[0][la1], 16, 0, 0);

  int cur = 0;
  for (int k0 = 0; k0 < K; k0 += 32) {
    __syncthreads();
    if (k0 + 32 < K) {
      int nxt = cur ^ 1;
      __builtin_amdgcn_global_load_lds((glb_void*)(gA0 + k0 + 32), (lds_void*)&As[nxt][la0], 16, 0, 0);
      __builtin_amdgcn_global_load_lds((glb_void*)(gA1 + k0 + 32), (lds_void*)&As[nxt][la1], 16, 0, 0);
      __builtin_amdgcn_global_load_lds((glb_void*)(gB0 + k0 + 32), (lds_void*)&Bs[nxt][la0], 16, 0, 0);
      __builtin_amdgcn_global_load_lds((glb_void*)(gB1 + k0 + 32), (lds_void*)&Bs[nxt][la1], 16, 0, 0);
    }
    b8v af[4], bfr[4];
#pragma unroll
    for (int mi = 0; mi < 4; ++mi)
      af[mi] = *(const b8v*)(&As[cur][(wr * 64 + mi * 16 + lrow) * 32 + quad * 8]);
#pragma unroll
    for (int ni = 0; ni < 4; ++ni)
      bfr[ni] = *(const b8v*)(&Bs[cur][(wc * 64 + ni * 16 + lrow) * 32 + quad * 8]);
#pragma unroll
    for (int mi = 0; mi < 4; ++mi)
#pragma unroll
      for (int ni = 0; ni < 4; ++ni)
        acc[mi][ni] = __builtin_amdgcn_mfma_f32_16x16x32_bf16(af[mi], bfr[ni], acc[mi][ni], 0, 0, 0);
    cur ^= 1;
  }

#pragma unroll
  for (int mi = 0; mi < 4; ++mi) {
#pragma unroll
    for (int ni = 0; ni < 4; ++ni) {
      int gcol = n0 + wc * 64 + ni * 16 + lrow;
      float bv = bias[gcol];
#pragma unroll
      for (int r = 0; r < 4; ++r) {
        int grow = m0 + wr * 64 + mi * 16 + quad * 4 + r;
        float v = acc[mi][ni][r] + bv;
        if (do_gelu) v = gelu_f(v);
        if (out_f32)
          ((float*)Cout)[(size_t)grow * N + gcol] = v;
        else
          ((u16*)Cout)[(size_t)grow * N + gcol] = f2b(v);
      }
    }
  }
}

// ---------------- split-K(2) GEMM: separate f32 partial buffers, no atomics --
// grid.z = 0/1 selects K-half and output buffer; bias added by split 0.
__global__ __launch_bounds__(256) void gemm_splitk2_kernel(const u16* __restrict__ A,
                                                           const u16* __restrict__ Bt,
                                                           const float* __restrict__ bias,
                                                           float* __restrict__ C0,
                                                           float* __restrict__ C1,
                                                           int M, int N, int K, int Kc) {
  __shared__ u16 As[2][128 * 32];
  __shared__ u16 Bs[2][128 * 32];
  const int tid = threadIdx.x;
  const int wave = tid >> 6, lane = tid & 63;
  const int wr = wave >> 1, wc = wave & 1;
  const int m0 = blockIdx.x * 128;
  const int n0 = blockIdx.y * 128;
  const int kz = blockIdx.z;
  const int lrow = lane & 15, quad = lane >> 4;
  const int srow = lane >> 2, sseg = lane & 3;

  const u16* gA0 = A  + (size_t)(m0 + wave * 32 + srow) * K + kz * Kc + sseg * 8;
  const u16* gA1 = gA0 + (size_t)16 * K;
  const u16* gB0 = Bt + (size_t)(n0 + wave * 32 + srow) * K + kz * Kc + sseg * 8;
  const u16* gB1 = gB0 + (size_t)16 * K;
  const int la0 = (wave * 32) * 32, la1 = (wave * 32 + 16) * 32;

  f4v acc[4][4] = {};

  __builtin_amdgcn_global_load_lds((glb_void*)gA0, (lds_void*)&As[0][la0], 16, 0, 0);
  __builtin_amdgcn_global_load_lds((glb_void*)gA1, (lds_void*)&As[0][la1], 16, 0, 0);
  __builtin_amdgcn_global_load_lds((glb_void*)gB0, (lds_void*)&Bs[0][la0], 16, 0, 0);
  __builtin_amdgcn_global_load_lds((glb_void*)gB1, (lds_void*)&Bs[0][la1], 16, 0, 0);

  int cur = 0;
  for (int k0 = 0; k0 < Kc; k0 += 32) {
    __syncthreads();
    if (k0 + 32 < Kc) {
      int nxt = cur ^ 1;
      __builtin_amdgcn_global_load_lds((glb_void*)(gA0 + k0 + 32), (lds_void*)&As[nxt][la0], 16, 0, 0);
      __builtin_amdgcn_global_load_lds((glb_void*)(gA1 + k0 + 32), (lds_void*)&As[nxt][la1], 16, 0, 0);
      __builtin_amdgcn_global_load_lds((glb_void*)(gB0 + k0 + 32), (lds_void*)&Bs[nxt][la0], 16, 0, 0);
      __builtin_amdgcn_global_load_lds((glb_void*)(gB1 + k0 + 32), (lds_void*)&Bs[nxt][la1], 16, 0, 0);
    }
    b8v af[4], bfr[4];
#pragma unroll
    for (int mi = 0; mi < 4; ++mi)
      af[mi] = *(const b8v*)(&As[cur][(wr * 64 + mi * 16 + lrow) * 32 + quad * 8]);
#pragma unroll
    for (int ni = 0; ni < 4; ++ni)
      bfr[ni] = *(const b8v*)(&Bs[cur][(wc * 64 + ni * 16 + lrow) * 32 + quad * 8]);
#pragma unroll
    for (int mi = 0; mi < 4; ++mi)
#pragma unroll
      for (int ni = 0; ni < 4; ++ni)
        acc[mi][ni] = __builtin_amdgcn_mfma_f32_16x16x32_bf16(af[mi], bfr[ni], acc[mi][ni], 0, 0, 0);
    cur ^= 1;
  }

  float* C = kz ? C1 : C0;
#pragma unroll
  for (int mi = 0; mi < 4; ++mi) {
#pragma unroll
    for (int ni = 0; ni < 4; ++ni) {
      int gcol = n0 + wc * 64 + ni * 16 + lrow;
      float bv = (kz == 0) ? bias[gcol] : 0.f;
#pragma unroll
      for (int r = 0; r < 4; ++r) {
        int grow = m0 + wr * 64 + mi * 16 + quad * 4 + r;
        C[(size_t)grow * N + gcol] = acc[mi][ni][r] + bv;
      }
    }
  }
}

// ---------------- MFMA flash attention (S^T / O^T formulation) ---------------
__global__ __launch_bounds__(256) void attn_mfma_kernel(const u16* __restrict__ qkv,
                                                        u16* __restrict__ y) {
  __shared__ u16 Ks[64 * 72];           // K row-major  [key][d]
  __shared__ u16 Vts[64 * 72];          // V transposed [d][key^swz]
  __shared__ u16 Ps[64 * 72];           // P row-major  [q_local][key]
  const int bh = blockIdx.x;
  const int b = bh >> 4, h = bh & 15;
  const int qt = 31 - blockIdx.y;       // heavy tiles first (LPT)
  const int tid = threadIdx.x, w = tid >> 6, lane = tid & 63;
  const int lrow = lane & 15, quad = lane >> 4;
  const int q0 = qt * 64;
  const int qg = q0 + w * 16 + lrow;

  b8v qf[2];
#pragma unroll
  for (int dc = 0; dc < 2; ++dc)
    qf[dc] = *(const b8v*)(qkv + (size_t)(b * T_SEQ + qg) * 3072 + h * 64 + dc * 32 + quad * 8);

  f4v oacc[4] = {};
  float mrun = -__builtin_inff(), lrun = 0.f;

  const int nch = qt + 1;
  for (int ct = 0; ct < nch; ++ct) {
    __syncthreads();
    {
      int r = tid >> 2, sg = tid & 3;
      const u16* src = qkv + (size_t)(b * T_SEQ + ct * 64 + r) * 3072 + h * 64 + 1024 + sg * 16;
      *(uint4*)(&Ks[r * 72 + sg * 16]) = *(const uint4*)(src);
      *(uint4*)(&Ks[r * 72 + sg * 16 + 8]) = *(const uint4*)(src + 8);
    }
    {
      int pr = tid >> 3, dsg = tid & 7;
      const u16* v0 = qkv + (size_t)(b * T_SEQ + ct * 64 + 2 * pr) * 3072 + h * 64 + 2048 + dsg * 8;
      uint4 a = *(const uint4*)(v0);
      uint4 bb = *(const uint4*)(v0 + 3072);
      uint32_t aw[4] = {a.x, a.y, a.z, a.w};
      uint32_t bw[4] = {bb.x, bb.y, bb.z, bb.w};
#pragma unroll
      for (int j = 0; j < 8; ++j) {
        int d = dsg * 8 + j;
        u16 ae = (u16)(aw[j >> 1] >> ((j & 1) * 16));
        u16 be = (u16)(bw[j >> 1] >> ((j & 1) * 16));
        int keyp = (2 * pr) ^ (((d >> 3) & 7) * 8);
        *(uint32_t*)(&Vts[d * 72 + keyp]) = (uint32_t)ae | ((uint32_t)be << 16);
      }
    }
    __syncthreads();

    f4v sacc[4] = {};
#pragma unroll
    for (int ks = 0; ks < 4; ++ks)
#pragma unroll
      for (int dc = 0; dc < 2; ++dc) {
        b8v kf = *(const b8v*)(&Ks[(ks * 16 + lrow) * 72 + dc * 32 + quad * 8]);
        sacc[ks] = __builtin_amdgcn_mfma_f32_16x16x32_bf16(kf, qf[dc], sacc[ks], 0, 0, 0);
      }

    bool diag = (ct == qt);
#pragma unroll
    for (int ks = 0; ks < 4; ++ks)
#pragma unroll
      for (int r = 0; r < 4; ++r) {
        float v = sacc[ks][r] * 0.125f;
        int key = ct * 64 + ks * 16 + quad * 4 + r;
        if (diag && key > qg) v = -__builtin_inff();
        sacc[ks][r] = v;
      }

    float rmax = sacc[0][0];
#pragma unroll
    for (int ks = 0; ks < 4; ++ks)
#pragma unroll
      for (int r = 0; r < 4; ++r) rmax = fmaxf(rmax, sacc[ks][r]);
    rmax = fmaxf(rmax, __shfl_xor(rmax, 16, 64));
    rmax = fmaxf(rmax, __shfl_xor(rmax, 32, 64));
    float mn = fmaxf(mrun, rmax);
    float al = __expf(mrun - mn);
    mrun = mn;
    float psum = 0.f;
#pragma unroll
    for (int ks = 0; ks < 4; ++ks)
#pragma unroll
      for (int r = 0; r < 4; ++r) {
        float p = __expf(sacc[ks][r] - mn);
        sacc[ks][r] = p;
        psum += p;
      }
    psum += __shfl_xor(psum, 16, 64);
    psum += __shfl_xor(psum, 32, 64);
    lrun = lrun * al + psum;
#pragma unroll
    for (int ds = 0; ds < 4; ++ds) oacc[ds] *= al;

#pragma unroll
    for (int ks = 0; ks < 4; ++ks) {
      ushort4 pw;
      pw.x = f2b(sacc[ks][0]); pw.y = f2b(sacc[ks][1]);
      pw.z = f2b(sacc[ks][2]); pw.w = f2b(sacc[ks][3]);
      *(ushort4*)(&Ps[(w * 16 + lrow) * 72 + ks * 16 + quad * 4]) = pw;
    }

    b8v pf[2];
#pragma unroll
    for (int kc = 0; kc < 2; ++kc)
      pf[kc] = *(const b8v*)(&Ps[(w * 16 + lrow) * 72 + kc * 32 + quad * 8]);
#pragma unroll
    for (int ds = 0; ds < 4; ++ds)
#pragma unroll
      for (int kc = 0; kc < 2; ++kc) {
        int d = ds * 16 + lrow;
        int off = (kc * 32 + quad * 8) ^ (((d >> 3) & 7) * 8);
        b8v vfv = *(const b8v*)(&Vts[d * 72 + off]);
        oacc[ds] = __builtin_amdgcn_mfma_f32_16x16x32_bf16(vfv, pf[kc], oacc[ds], 0, 0, 0);
      }
  }

  float rinv = 1.0f / lrun;
  u16* yrow = y + (size_t)(b * T_SEQ + qg) * DMODEL + h * 64;
#pragma unroll
  for (int ds = 0; ds < 4; ++ds) {
    ushort4 ov;
    ov.x = f2b(oacc[ds][0] * rinv);
    ov.y = f2b(oacc[ds][1] * rinv);
    ov.z = f2b(oacc[ds][2] * rinv);
    ov.w = f2b(oacc[ds][3] * rinv);
    *(ushort4*)(yrow + ds * 16 + quad * 4) = ov;
  }
}

// ----------------------------------------------------------------------------
extern "C" void kernel_launch(void* const* d_in, const int* in_sizes, int n_in,
                              void* d_out, int out_size, void* d_ws, size_t ws_size,
                              hipStream_t stream) {
  const float* z      = (const float*)d_in[0];
  const float* t      = (const float*)d_in[1];
  const float* w_t1   = (const float*)d_in[2];
  const float* b_t1   = (const float*)d_in[3];
  const float* w_t2   = (const float*)d_in[4];
  const float* b_t2   = (const float*)d_in[5];
  const float* ln_a_w = (const float*)d_in[6];
  const float* ln_a_b = (const float*)d_in[7];
  const float* w_attn = (const float*)d_in[8];
  const float* b_attn = (const float*)d_in[9];
  const float* w_proj = (const float*)d_in[10];
  const float* b_proj = (const float*)d_in[11];
  const float* ln_m_w = (const float*)d_in[12];
  const float* ln_m_b = (const float*)d_in[13];
  const float* w_fc   = (const float*)d_in[14];
  const float* b_fc   = (const float*)d_in[15];
  const float* w_fc2  = (const float*)d_in[16];
  const float* b_fc2  = (const float*)d_in[17];

  char* ws = (char*)d_ws;
  float* temb  = (float*)ws;
  u16* wT_attn = (u16*)(ws + 1024);
  u16* wT_proj = wT_attn + (size_t)3072 * 1088;
  u16* wT_fc   = wT_proj + (size_t)1024 * 1024;
  u16* wT_fc2  = wT_fc   + (size_t)4096 * 1088;
  u16* xbuf    = wT_fc2  + (size_t)1024 * 4096;
  u16* big     = xbuf    + (size_t)4096 * 1088;   // qkv, later fc output g
  u16* ybuf    = big     + (size_t)4096 * 4096;
  float* p0    = (float*)(ybuf + (size_t)4096 * 1024);   // f32 partials [4096][1024]
  float* p1    = p0 + (size_t)4096 * 1024;

  time_mlp_kernel<<<dim3(1), dim3(128), 0, stream>>>(t, w_t1, b_t1, w_t2, b_t2, temb);

  transpose_kernel<<<dim3(3072 / 32, 1088 / 32), dim3(256), 0, stream>>>(w_attn, wT_attn, 1088, 3072);
  transpose_kernel<<<dim3(1024 / 32, 1024 / 32), dim3(256), 0, stream>>>(w_proj, wT_proj, 1024, 1024);
  transpose_kernel<<<dim3(4096 / 32, 1088 / 32), dim3(256), 0, stream>>>(w_fc, wT_fc, 1088, 4096);
  transpose_kernel<<<dim3(1024 / 32, 4096 / 32), dim3(256), 0, stream>>>(w_fc2, wT_fc2, 4096, 1024);

  ln_concat_kernel<<<dim3(MROWS), dim3(256), 0, stream>>>(
      z, (const float*)nullptr, (const u16*)nullptr, temb, ln_a_w, ln_a_b, xbuf, 1);

  gemm_bt_kernel<<<dim3(MROWS / 128, 3072 / 128), dim3(256), 0, stream>>>(
      xbuf, wT_attn, b_attn, big, MROWS, 3072, 1088, 0, 0);

  attn_mfma_kernel<<<dim3(32, 32), dim3(256), 0, stream>>>(big, ybuf);

  // proj: split-K=2 into p0/p1 (512 blocks)
  gemm_splitk2_kernel<<<dim3(MROWS / 128, 1024 / 128, 2), dim3(256), 0, stream>>>(
      ybuf, wT_proj, b_proj, p0, p1, MROWS, 1024, 1024, 512);

  // ln_m reads h = p0 + p1
  ln_concat_kernel<<<dim3(MROWS), dim3(256), 0, stream>>>(
      p0, p1, (const u16*)nullptr, temb, ln_m_w, ln_m_b, xbuf, 2);

  gemm_bt_kernel<<<dim3(MROWS / 128, 4096 / 128), dim3(256), 0, stream>>>(
      xbuf, wT_fc, b_fc, big, MROWS, 4096, 1088, 1, 0);

  // fc2: split-K=2 into p0/p1 (reused; proj partials dead after ln_m)
  gemm_splitk2_kernel<<<dim3(MROWS / 128, 1024 / 128, 2), dim3(256), 0, stream>>>(
      big, wT_fc2, b_fc2, p0, p1, MROWS, 1024, 4096, 2048);

  // combine: d_out = p0 + p1
  add2_kernel<<<dim3((MROWS * 1024 / 4 + 255) / 256), dim3(256), 0, stream>>>(
      (const float4*)p0, (const float4*)p1, (float4*)d_out, MROWS * 1024 / 4);
}